// Round 3
// baseline (731.735 us; speedup 1.0000x reference)
//
#include <hip/hip_runtime.h>
#include <cstdint>

// Problem constants
#define BB 4
#define NN 16384
#define CC 512
#define HH 16
#define DD 32
#define HID 2048
#define MTOT (BB * NN)        // 65536 tokens
#define MCHUNK 16384          // GEMM row chunk (bounds ws usage)

typedef __bf16 bf16_t;
typedef __bf16 bf16x8 __attribute__((ext_vector_type(8)));
typedef __bf16 bf16x4 __attribute__((ext_vector_type(4)));
typedef float  f32x4  __attribute__((ext_vector_type(4)));

// ---- async global->LDS 16B ----
__device__ __forceinline__ void gload_lds16(const void* g, void* l) {
  auto gp = reinterpret_cast<const __attribute__((address_space(1))) char*>(
      reinterpret_cast<uintptr_t>(g));
  auto lp = reinterpret_cast<__attribute__((address_space(3))) char*>(
      reinterpret_cast<uintptr_t>(l));
  __builtin_amdgcn_global_load_lds(gp, lp, 16, 0, 0);
}

// ---- fp32 -> bf16 weight convert ----
__global__ __launch_bounds__(256) void cvt_bf16_kernel(const float* __restrict__ src,
                                                       bf16_t* __restrict__ dst) {
  const long i = ((long)blockIdx.x * 256 + threadIdx.x) * 4;
  const f32x4 v = *(const f32x4*)(src + i);
  bf16x4 o;
  o[0] = (bf16_t)v[0]; o[1] = (bf16_t)v[1]; o[2] = (bf16_t)v[2]; o[3] = (bf16_t)v[3];
  *(bf16x4*)(dst + i) = o;
}

// ---- LayerNorm1: one wave per token; lane owns 8 contiguous channels ----
__global__ __launch_bounds__(256) void norm1_kernel(const float* __restrict__ x,
                                                    const float* __restrict__ w,
                                                    const float* __restrict__ bvec,
                                                    bf16_t* __restrict__ h) {
  const int wv = threadIdx.x >> 6, l = threadIdx.x & 63;
  const long tok = (long)blockIdx.x * 4 + wv;
  const int c0 = l * 8;
  const f32x4 a = *(const f32x4*)(x + tok * CC + c0);
  const f32x4 b = *(const f32x4*)(x + tok * CC + c0 + 4);
  float v[8];
#pragma unroll
  for (int i = 0; i < 4; ++i) { v[i] = a[i]; v[4 + i] = b[i]; }
  float s = 0.f, s2 = 0.f;
#pragma unroll
  for (int i = 0; i < 8; ++i) { s += v[i]; s2 += v[i] * v[i]; }
  for (int off = 32; off; off >>= 1) { s += __shfl_xor(s, off); s2 += __shfl_xor(s2, off); }
  const float mean = s * (1.f / CC);
  const float var  = fmaxf(s2 * (1.f / CC) - mean * mean, 0.f);
  const float rstd = rsqrtf(var + 1e-5f);
  const f32x4 w0 = *(const f32x4*)(w + c0), w1 = *(const f32x4*)(w + c0 + 4);
  const f32x4 b0 = *(const f32x4*)(bvec + c0), b1 = *(const f32x4*)(bvec + c0 + 4);
  bf16x8 o;
#pragma unroll
  for (int i = 0; i < 4; ++i) {
    o[i]     = (bf16_t)(w0[i] * (v[i] - mean) * rstd + b0[i]);
    o[4 + i] = (bf16_t)(w1[i] * (v[4 + i] - mean) * rstd + b1[i]);
  }
  *(bf16x8*)(h + tok * CC + c0) = o;
}

// ---- kv partial: block = (b,head,chunk of 256 tokens) ----
__global__ __launch_bounds__(256) void kv_partial_kernel(const bf16_t* __restrict__ h,
                                                         const float* __restrict__ klw,
                                                         const float* __restrict__ klb,
                                                         const float* __restrict__ vlw,
                                                         const float* __restrict__ vlb,
                                                         float* __restrict__ kvp) {
  __shared__ bf16_t hb[256][32];
  __shared__ bf16_t kb[256][32];
  __shared__ bf16_t vb[256][32];
  const int tid = threadIdx.x;
  const int bh = blockIdx.x >> 6, chunk = blockIdx.x & 63;
  const int head = bh & 15;
  const int b = bh >> 4;
  const long tok0 = ((long)b << 14) + chunk * 256;
  const bf16_t* src = h + tok0 * CC + head * DD;
#pragma unroll
  for (int j = 0; j < 4; ++j) {
    const int row = j * 64 + (tid >> 2);
    *(bf16x8*)&hb[row][(tid & 3) * 8] = *(const bf16x8*)(src + (long)row * CC + (tid & 3) * 8);
  }
  __syncthreads();
  {
    float hv[32]; float s = 0.f, s2 = 0.f;
#pragma unroll
    for (int d = 0; d < 32; ++d) { hv[d] = (float)hb[tid][d]; s += hv[d]; s2 += hv[d] * hv[d]; }
    const float mean = s * (1.f / 32.f);
    const float varu = fmaxf((s2 - 32.f * mean * mean) * (1.f / 31.f), 0.f);
    const float inv = 1.f / (sqrtf(varu) + 1e-5f);   // torch.std semantics
#pragma unroll
    for (int d = 0; d < 32; ++d) {
      const float t = (hv[d] - mean) * inv;
      kb[tid][d] = (bf16_t)(klw[head * DD + d] * t + klb[head * DD + d]);
      vb[tid][d] = (bf16_t)(vlw[head * DD + d] * t + vlb[head * DD + d]);
    }
  }
  __syncthreads();
  const int g = tid >> 6, l = tid & 63;
  const int d0 = (l >> 3) * 4, e0 = (l & 7) * 4;
  float a[4][4] = {};
  for (int t = g; t < 256; t += 4) {
    bf16x4 kq = *(const bf16x4*)&kb[t][d0];
    bf16x4 vq = *(const bf16x4*)&vb[t][e0];
    float kf[4], vf[4];
#pragma unroll
    for (int i2 = 0; i2 < 4; ++i2) { kf[i2] = (float)kq[i2]; vf[i2] = (float)vq[i2]; }
#pragma unroll
    for (int i2 = 0; i2 < 4; ++i2)
#pragma unroll
      for (int j2 = 0; j2 < 4; ++j2) a[i2][j2] += kf[i2] * vf[j2];
  }
  __syncthreads();
  float* scratch = (float*)&hb[0][0];
  if (g) {
#pragma unroll
    for (int i2 = 0; i2 < 4; ++i2)
#pragma unroll
      for (int j2 = 0; j2 < 4; ++j2)
        scratch[((g - 1) * 64 + l) * 16 + i2 * 4 + j2] = a[i2][j2];
  }
  __syncthreads();
  if (!g) {
#pragma unroll
    for (int gg = 0; gg < 3; ++gg)
#pragma unroll
      for (int i2 = 0; i2 < 4; ++i2)
#pragma unroll
        for (int j2 = 0; j2 < 4; ++j2)
          a[i2][j2] += scratch[(gg * 64 + l) * 16 + i2 * 4 + j2];
    float* dst = kvp + ((long)(bh * 64 + chunk) << 10);
#pragma unroll
    for (int i2 = 0; i2 < 4; ++i2) {
      f32x4 st;
      st[0] = a[i2][0]; st[1] = a[i2][1]; st[2] = a[i2][2]; st[3] = a[i2][3];
      *(f32x4*)&dst[(d0 + i2) * 32 + e0] = st;
    }
  }
}

// ---- kv reduce over 64 chunks, /N, store TRANSPOSED bf16: kvT[bh][e][d] ----
__global__ __launch_bounds__(256) void kv_reduce_kernel(const float* __restrict__ kvp,
                                                        bf16_t* __restrict__ kvT) {
  const int bh = blockIdx.x;
  const int i4 = threadIdx.x * 4;
  const int d = i4 >> 5, e0 = i4 & 31;
  float s[4] = {};
  const float* p = kvp + ((long)bh << 16) + i4;
  for (int ch = 0; ch < 64; ++ch) {
    const f32x4 t = *(const f32x4*)(p + (ch << 10));
    s[0] += t[0]; s[1] += t[1]; s[2] += t[2]; s[3] += t[3];
  }
  const float sc = 1.f / (float)NN;
  bf16_t* q = kvT + ((long)bh << 10);
#pragma unroll
  for (int j = 0; j < 4; ++j) q[(e0 + j) * 32 + d] = (bf16_t)(s[j] * sc);
}

// ---- fused: MFMA attn + residuals -> x2 (d_out fp32), LN2 -> m (bf16) ----
// block = 32 tokens, 4 waves. kvT read direct from global (L2-resident, 128KB).
#define ASTRIDE 520            // padded attn_s row (elems), 16B-aligned rows
__global__ __launch_bounds__(256) void attn_fused_kernel(const float* __restrict__ x,
                                                         const bf16_t* __restrict__ h,
                                                         const bf16_t* __restrict__ kvTg,
                                                         const float* __restrict__ n2w,
                                                         const float* __restrict__ n2b,
                                                         float* __restrict__ xout,
                                                         bf16_t* __restrict__ mout) {
  __shared__ bf16_t attn_s[32 * ASTRIDE];      // 33280 B -> 4 blocks/CU
  const int tid = threadIdx.x;
  const int wv = tid >> 6, lane = tid & 63;
  const int lr = lane & 15, kg = lane >> 4;
  const long tok0 = (long)blockIdx.x * 32;
  const int b = (int)(tok0 >> 14);
  const bf16_t* kvsrc = kvTg + ((long)b << 14);

  // phase 1: per-head MFMA  attn[t][e] = sum_d q[t][d] * kv[d][e]
  {
    const int tt = wv & 1, hh = wv >> 1;
    const bf16_t* arow = h + (tok0 + tt * 16 + lr) * (long)CC + kg * 8;
    const f32x4 zero = {};
#pragma unroll
    for (int hi = 0; hi < 8; ++hi) {
      const int hd = hh * 8 + hi;
      const bf16_t* kvh = kvsrc + (hd << 10) + kg * 8;
      const bf16x8 af = *(const bf16x8*)(arow + hd * DD);
      const bf16x8 b0 = *(const bf16x8*)(kvh + lr * 32);
      const bf16x8 b1 = *(const bf16x8*)(kvh + (16 + lr) * 32);
      const f32x4 a0 = __builtin_amdgcn_mfma_f32_16x16x32_bf16(af, b0, zero, 0, 0, 0);
      const f32x4 a1 = __builtin_amdgcn_mfma_f32_16x16x32_bf16(af, b1, zero, 0, 0, 0);
      const int rbase = tt * 16 + kg * 4;
#pragma unroll
      for (int rg = 0; rg < 4; ++rg) {
        attn_s[(rbase + rg) * ASTRIDE + hd * 32 + lr]      = (bf16_t)a0[rg];
        attn_s[(rbase + rg) * ASTRIDE + hd * 32 + 16 + lr] = (bf16_t)a1[rg];
      }
    }
  }
  __syncthreads();

  // phase 2: wave-per-token residual + LN2 (8 tokens per wave)
  const int c0 = lane * 8;
  const f32x4 w0 = *(const f32x4*)(n2w + c0), w1 = *(const f32x4*)(n2w + c0 + 4);
  const f32x4 bb0 = *(const f32x4*)(n2b + c0), bb1 = *(const f32x4*)(n2b + c0 + 4);
  for (int it = 0; it < 8; ++it) {
    const int tl = wv * 8 + it;
    const long tok = tok0 + tl;
    const f32x4 xa = *(const f32x4*)(x + tok * CC + c0);
    const f32x4 xb = *(const f32x4*)(x + tok * CC + c0 + 4);
    const bf16x8 hv = *(const bf16x8*)(h + tok * CC + c0);
    const bf16x8 av = *(const bf16x8*)&attn_s[tl * ASTRIDE + c0];
    float x2[8];
#pragma unroll
    for (int i = 0; i < 4; ++i) {
      x2[i]     = xa[i] + (float)hv[i]     + (float)av[i];
      x2[4 + i] = xb[i] + (float)hv[4 + i] + (float)av[4 + i];
    }
    float s = 0.f, s2 = 0.f;
#pragma unroll
    for (int i = 0; i < 8; ++i) { s += x2[i]; s2 += x2[i] * x2[i]; }
    for (int off = 32; off; off >>= 1) { s += __shfl_xor(s, off); s2 += __shfl_xor(s2, off); }
    const float mean = s * (1.f / CC);
    const float var  = fmaxf(s2 * (1.f / CC) - mean * mean, 0.f);
    const float rstd = rsqrtf(var + 1e-5f);
    f32x4 oa, ob;
    bf16x8 om;
#pragma unroll
    for (int i = 0; i < 4; ++i) {
      oa[i] = x2[i]; ob[i] = x2[4 + i];
      om[i]     = (bf16_t)(w0[i] * (x2[i] - mean) * rstd + bb0[i]);
      om[4 + i] = (bf16_t)(w1[i] * (x2[4 + i] - mean) * rstd + bb1[i]);
    }
    *(f32x4*)(xout + tok * CC + c0) = oa;
    *(f32x4*)(xout + tok * CC + c0 + 4) = ob;
    *(bf16x8*)(mout + tok * CC + c0) = om;
  }
}

// ---- 256x256 GEMM, BK=32, 8 waves, distance-2 prefetch + counted vmcnt ----
// out[i][j] = sum_k A[i][k] * Bw[j][k]; both A and Bw are row-major with K contiguous.
template <int K, int NOUT, bool GELU>
__global__ __launch_bounds__(512, 2) void gemm256_kernel(const bf16_t* __restrict__ A,
                                                         const bf16_t* __restrict__ Bw,
                                                         const float* __restrict__ bias,
                                                         bf16_t* __restrict__ outb,
                                                         float* __restrict__ outf) {
  // 3 buffers x (A 16KB + B 16KB) = 96KB
  __shared__ bf16_t lds[3 * 16384];
  const int tid = threadIdx.x;
  const int wid = tid >> 6, lane = tid & 63;
  const int wm = wid >> 2, wn = wid & 3;
  const int lr = lane & 15, kg = lane >> 4;
  constexpr int NTILE = NOUT / 256;
  constexpr int NT = K / 32;              // K-tiles

  // XCD-aware swizzle (grid % 8 == 0 for all our shapes)
  int bid = blockIdx.x;
  const int q = gridDim.x >> 3;
  bid = (bid & 7) * q + (bid >> 3);
  const int bx = bid % NTILE;
  const long by = bid / NTILE;
  const long row0 = by * 256;
  const long col0 = (long)bx * 256;

  // staging map: thread tid covers LDS byte tid*16 (+8192 for second row-half)
  const int srow = tid >> 2;              // 0..127
  const int scol = (tid & 3) * 8;         // elems within 32-wide K slab
  const bf16_t* gA = A + (row0 + srow) * (long)K + scol;
  const bf16_t* gB = Bw + (col0 + srow) * (long)K + scol;
  char* ldsb = (char*)lds;

#define STAGE256(bufi, kt) do {                                         \
    char* bb_ = ldsb + (bufi) * 32768;                                  \
    gload_lds16(gA + (kt) * 32,                bb_ + tid * 16);         \
    gload_lds16(gA + 128L * K + (kt) * 32,     bb_ + 8192 + tid * 16);  \
    gload_lds16(gB + (kt) * 32,                bb_ + 16384 + tid * 16); \
    gload_lds16(gB + 128L * K + (kt) * 32,     bb_ + 24576 + tid * 16); \
  } while (0)

  f32x4 acc[8][4] = {};

  // prologue: stage tiles 0,1; wait tile 0; barrier
  STAGE256(0, 0);
  STAGE256(1, 1);
  asm volatile("s_waitcnt vmcnt(4)" ::: "memory");
  __builtin_amdgcn_s_barrier();

  for (int t = 0; t < NT; ++t) {
    const int cur = t % 3;
    if (t + 2 < NT) STAGE256((t + 2) % 3, t + 2);
    const char* ab = (const char*)ldsb + cur * 32768;
    const char* bb = ab + 16384;
    bf16x8 af[8], bf[4];
#pragma unroll
    for (int m = 0; m < 8; ++m)
      af[m] = *(const bf16x8*)(ab + (wm * 128 + m * 16 + lr) * 64 + kg * 16);
#pragma unroll
    for (int n = 0; n < 4; ++n)
      bf[n] = *(const bf16x8*)(bb + (wn * 64 + n * 16 + lr) * 64 + kg * 16);
    __builtin_amdgcn_s_setprio(1);
#pragma unroll
    for (int m = 0; m < 8; ++m)
#pragma unroll
      for (int n = 0; n < 4; ++n)
        acc[m][n] = __builtin_amdgcn_mfma_f32_16x16x32_bf16(af[m], bf[n], acc[m][n], 0, 0, 0);
    __builtin_amdgcn_s_setprio(0);
    if (t + 1 < NT) {
      if (t + 2 < NT) {
        asm volatile("s_waitcnt vmcnt(4)" ::: "memory");  // t+1's 4 loads arrived
      } else {
        asm volatile("s_waitcnt vmcnt(0)" ::: "memory");  // tail drain
      }
      __builtin_amdgcn_s_barrier();
    }
  }
#undef STAGE256

  // epilogue: D row = (lane>>4)*4 + reg, col = lane&15
  const int orow = kg * 4;
#pragma unroll
  for (int n = 0; n < 4; ++n) {
    const long col = col0 + wn * 64 + n * 16 + lr;
    const float bs = bias[col];
#pragma unroll
    for (int m = 0; m < 8; ++m) {
#pragma unroll
      for (int rg = 0; rg < 4; ++rg) {
        const long row = row0 + wm * 128 + m * 16 + orow + rg;
        const float v = acc[m][n][rg] + bs;
        if constexpr (GELU) {
          const float u = 0.7978845608028654f * (v + 0.044715f * v * v * v);
          const float gv = v / (1.f + __expf(-2.f * u));
          outb[row * NOUT + col] = (bf16_t)gv;
        } else {
          outf[row * NOUT + col] += v;   // residual RMW onto x2 already in d_out
        }
      }
    }
  }
}

extern "C" void kernel_launch(void* const* d_in, const int* in_sizes, int n_in,
                              void* d_out, int out_size, void* d_ws, size_t ws_size,
                              hipStream_t stream) {
  const float* x   = (const float*)d_in[0];
  const float* n1w = (const float*)d_in[2];
  const float* n1b = (const float*)d_in[3];
  const float* klw = (const float*)d_in[4];
  const float* klb = (const float*)d_in[5];
  const float* vlw = (const float*)d_in[6];
  const float* vlb = (const float*)d_in[7];
  const float* n2w = (const float*)d_in[8];
  const float* n2b = (const float*)d_in[9];
  const float* w1f = (const float*)d_in[10];
  const float* b1  = (const float*)d_in[11];
  const float* w2f = (const float*)d_in[12];
  const float* b2  = (const float*)d_in[13];
  float* out = (float*)d_out;

  char* ws = (char*)d_ws;
  bf16_t* h   = (bf16_t*)(ws);                           // 64 MiB
  bf16_t* mb  = (bf16_t*)(ws + (size_t)67108864);        // 64 MiB
  bf16_t* act = (bf16_t*)(ws + (size_t)134217728);       // 64 MiB
  bf16_t* w1  = (bf16_t*)(ws + (size_t)201326592);       // 2 MiB
  bf16_t* w2  = (bf16_t*)(ws + (size_t)203423744);       // 2 MiB
  float*  kvp = (float*)(ws + (size_t)205520896);        // 16 MiB
  bf16_t* kvT = (bf16_t*)(ws + (size_t)222298112);       // 128 KiB

  cvt_bf16_kernel<<<1024, 256, 0, stream>>>(w1f, w1);
  cvt_bf16_kernel<<<1024, 256, 0, stream>>>(w2f, w2);
  norm1_kernel<<<MTOT / 4, 256, 0, stream>>>(x, n1w, n1b, h);
  kv_partial_kernel<<<BB * HH * 64, 256, 0, stream>>>(h, klw, klb, vlw, vlb, kvp);
  kv_reduce_kernel<<<BB * HH, 256, 0, stream>>>(kvp, kvT);
  attn_fused_kernel<<<MTOT / 32, 256, 0, stream>>>(x, h, kvT, n2w, n2b, out, mb);
  for (int ch = 0; ch < MTOT / MCHUNK; ++ch) {
    gemm256_kernel<CC, HID, true><<<(MCHUNK / 256) * (HID / 256), 512, 0, stream>>>(
        mb + (long)ch * MCHUNK * CC, w1, b1, act, nullptr);
    gemm256_kernel<HID, CC, false><<<(MCHUNK / 256) * (CC / 256), 512, 0, stream>>>(
        act, w2, b2, nullptr, out + (long)ch * MCHUNK * CC);
  }
}

// Round 4
// 633.585 us; speedup vs baseline: 1.1549x; 1.1549x over previous
//
#include <hip/hip_runtime.h>
#include <cstdint>

// Problem constants
#define BB 4
#define NN 16384
#define CC 512
#define HH 16
#define DD 32
#define HID 2048
#define MTOT (BB * NN)        // 65536 tokens
#define MCHUNK 16384          // GEMM row chunk (bounds ws usage)

typedef __bf16 bf16_t;
typedef __bf16 bf16x8 __attribute__((ext_vector_type(8)));
typedef __bf16 bf16x4 __attribute__((ext_vector_type(4)));
typedef float  f32x4  __attribute__((ext_vector_type(4)));

// ---- async global->LDS 16B ----
__device__ __forceinline__ void gload_lds16(const void* g, void* l) {
  auto gp = reinterpret_cast<const __attribute__((address_space(1))) char*>(
      reinterpret_cast<uintptr_t>(g));
  auto lp = reinterpret_cast<__attribute__((address_space(3))) char*>(
      reinterpret_cast<uintptr_t>(l));
  __builtin_amdgcn_global_load_lds(gp, lp, 16, 0, 0);
}

// ---- fp32 -> bf16 weight convert ----
__global__ __launch_bounds__(256) void cvt_bf16_kernel(const float* __restrict__ src,
                                                       bf16_t* __restrict__ dst) {
  const long i = ((long)blockIdx.x * 256 + threadIdx.x) * 4;
  const f32x4 v = *(const f32x4*)(src + i);
  bf16x4 o;
  o[0] = (bf16_t)v[0]; o[1] = (bf16_t)v[1]; o[2] = (bf16_t)v[2]; o[3] = (bf16_t)v[3];
  *(bf16x4*)(dst + i) = o;
}

// ---- LayerNorm1: one wave per token; lane owns 8 contiguous channels ----
__global__ __launch_bounds__(256) void norm1_kernel(const float* __restrict__ x,
                                                    const float* __restrict__ w,
                                                    const float* __restrict__ bvec,
                                                    bf16_t* __restrict__ h) {
  const int wv = threadIdx.x >> 6, l = threadIdx.x & 63;
  const long tok = (long)blockIdx.x * 4 + wv;
  const int c0 = l * 8;
  const f32x4 a = *(const f32x4*)(x + tok * CC + c0);
  const f32x4 b = *(const f32x4*)(x + tok * CC + c0 + 4);
  float v[8];
#pragma unroll
  for (int i = 0; i < 4; ++i) { v[i] = a[i]; v[4 + i] = b[i]; }
  float s = 0.f, s2 = 0.f;
#pragma unroll
  for (int i = 0; i < 8; ++i) { s += v[i]; s2 += v[i] * v[i]; }
  for (int off = 32; off; off >>= 1) { s += __shfl_xor(s, off); s2 += __shfl_xor(s2, off); }
  const float mean = s * (1.f / CC);
  const float var  = fmaxf(s2 * (1.f / CC) - mean * mean, 0.f);
  const float rstd = rsqrtf(var + 1e-5f);
  const f32x4 w0 = *(const f32x4*)(w + c0), w1 = *(const f32x4*)(w + c0 + 4);
  const f32x4 b0 = *(const f32x4*)(bvec + c0), b1 = *(const f32x4*)(bvec + c0 + 4);
  bf16x8 o;
#pragma unroll
  for (int i = 0; i < 4; ++i) {
    o[i]     = (bf16_t)(w0[i] * (v[i] - mean) * rstd + b0[i]);
    o[4 + i] = (bf16_t)(w1[i] * (v[4 + i] - mean) * rstd + b1[i]);
  }
  *(bf16x8*)(h + tok * CC + c0) = o;
}

// ---- kv partial: block = (b,head,chunk of 256 tokens) ----
// k/v LDS tiles stored with per-row XOR chunk swizzle -> 2-way (free) on writes;
// outer-product reads are same-row broadcasts (free).
__global__ __launch_bounds__(256) void kv_partial_kernel(const bf16_t* __restrict__ h,
                                                         const float* __restrict__ klw,
                                                         const float* __restrict__ klb,
                                                         const float* __restrict__ vlw,
                                                         const float* __restrict__ vlb,
                                                         float* __restrict__ kvp) {
  __shared__ bf16_t kb[256 * 32];
  __shared__ bf16_t vb[256 * 32];
  __shared__ float scratch[192 * 16];   // 12KB
  const int tid = threadIdx.x;
  const int bh = blockIdx.x >> 6, chunk = blockIdx.x & 63;
  const int head = bh & 15;
  const int b = bh >> 4;
  const long tok0 = ((long)b << 14) + chunk * 256;
  // each lane loads its own token's 32-ch row straight from global
  const bf16_t* src = h + (tok0 + tid) * (long)CC + head * DD;
  float hv[32];
  {
    float s = 0.f, s2 = 0.f;
#pragma unroll
    for (int c = 0; c < 4; ++c) {
      const bf16x8 r = *(const bf16x8*)(src + c * 8);
#pragma unroll
      for (int j = 0; j < 8; ++j) {
        hv[c * 8 + j] = (float)r[j]; s += hv[c * 8 + j]; s2 += hv[c * 8 + j] * hv[c * 8 + j];
      }
    }
    const float mean = s * (1.f / 32.f);
    const float varu = fmaxf((s2 - 32.f * mean * mean) * (1.f / 31.f), 0.f);
    const float inv = 1.f / (sqrtf(varu) + 1e-5f);   // torch.std semantics
    const int sx = (tid >> 1) & 3;
#pragma unroll
    for (int c = 0; c < 4; ++c) {
      bf16x8 kc, vc;
#pragma unroll
      for (int j = 0; j < 8; ++j) {
        const int d = c * 8 + j;
        const float t = (hv[d] - mean) * inv;
        kc[j] = (bf16_t)(klw[head * DD + d] * t + klb[head * DD + d]);
        vc[j] = (bf16_t)(vlw[head * DD + d] * t + vlb[head * DD + d]);
      }
      *(bf16x8*)((char*)kb + tid * 64 + ((c ^ sx) * 16)) = kc;
      *(bf16x8*)((char*)vb + tid * 64 + ((c ^ sx) * 16)) = vc;
    }
  }
  __syncthreads();
  const int g = tid >> 6, l = tid & 63;
  const int d0 = (l >> 3) * 4, e0 = (l & 7) * 4;
  const int ck = (l >> 3) >> 1, hk = (l >> 3) & 1;
  const int ce = (l & 7) >> 1, he = l & 1;
  float a[4][4] = {};
  for (int t = g; t < 256; t += 4) {
    const int tx = (t >> 1) & 3;
    const bf16x4 kq = *(const bf16x4*)((const char*)kb + t * 64 + ((ck ^ tx) * 16) + hk * 8);
    const bf16x4 vq = *(const bf16x4*)((const char*)vb + t * 64 + ((ce ^ tx) * 16) + he * 8);
    float kf[4], vf[4];
#pragma unroll
    for (int i2 = 0; i2 < 4; ++i2) { kf[i2] = (float)kq[i2]; vf[i2] = (float)vq[i2]; }
#pragma unroll
    for (int i2 = 0; i2 < 4; ++i2)
#pragma unroll
      for (int j2 = 0; j2 < 4; ++j2) a[i2][j2] += kf[i2] * vf[j2];
  }
  __syncthreads();
  if (g) {
#pragma unroll
    for (int i2 = 0; i2 < 4; ++i2)
#pragma unroll
      for (int j2 = 0; j2 < 4; ++j2)
        scratch[((g - 1) * 64 + l) * 16 + i2 * 4 + j2] = a[i2][j2];
  }
  __syncthreads();
  if (!g) {
#pragma unroll
    for (int gg = 0; gg < 3; ++gg)
#pragma unroll
      for (int i2 = 0; i2 < 4; ++i2)
#pragma unroll
        for (int j2 = 0; j2 < 4; ++j2)
          a[i2][j2] += scratch[(gg * 64 + l) * 16 + i2 * 4 + j2];
    float* dst = kvp + ((long)(bh * 64 + chunk) << 10);
#pragma unroll
    for (int i2 = 0; i2 < 4; ++i2) {
      f32x4 st;
      st[0] = a[i2][0]; st[1] = a[i2][1]; st[2] = a[i2][2]; st[3] = a[i2][3];
      *(f32x4*)&dst[(d0 + i2) * 32 + e0] = st;
    }
  }
}

// ---- kv reduce over 64 chunks, /N, store TRANSPOSED bf16: kvT[bh][e][d] ----
__global__ __launch_bounds__(256) void kv_reduce_kernel(const float* __restrict__ kvp,
                                                        bf16_t* __restrict__ kvT) {
  const int bh = blockIdx.x;
  const int i4 = threadIdx.x * 4;
  const int d = i4 >> 5, e0 = i4 & 31;
  float s[4] = {};
  const float* p = kvp + ((long)bh << 16) + i4;
  for (int ch = 0; ch < 64; ++ch) {
    const f32x4 t = *(const f32x4*)(p + (ch << 10));
    s[0] += t[0]; s[1] += t[1]; s[2] += t[2]; s[3] += t[3];
  }
  const float sc = 1.f / (float)NN;
  bf16_t* q = kvT + ((long)bh << 10);
#pragma unroll
  for (int j = 0; j < 4; ++j) q[(e0 + j) * 32 + d] = (bf16_t)(s[j] * sc);
}

// ---- fused: MFMA attn + residuals -> x2 (d_out fp32), LN2 -> m (bf16) ----
#define ASTRIDE 520
__global__ __launch_bounds__(256) void attn_fused_kernel(const float* __restrict__ x,
                                                         const bf16_t* __restrict__ h,
                                                         const bf16_t* __restrict__ kvTg,
                                                         const float* __restrict__ n2w,
                                                         const float* __restrict__ n2b,
                                                         float* __restrict__ xout,
                                                         bf16_t* __restrict__ mout) {
  __shared__ bf16_t attn_s[32 * ASTRIDE];
  const int tid = threadIdx.x;
  const int wv = tid >> 6, lane = tid & 63;
  const int lr = lane & 15, kg = lane >> 4;
  const long tok0 = (long)blockIdx.x * 32;
  const int b = (int)(tok0 >> 14);
  const bf16_t* kvsrc = kvTg + ((long)b << 14);

  {
    const int tt = wv & 1, hh = wv >> 1;
    const bf16_t* arow = h + (tok0 + tt * 16 + lr) * (long)CC + kg * 8;
    const f32x4 zero = {};
#pragma unroll
    for (int hi = 0; hi < 8; ++hi) {
      const int hd = hh * 8 + hi;
      const bf16_t* kvh = kvsrc + (hd << 10) + kg * 8;
      const bf16x8 af = *(const bf16x8*)(arow + hd * DD);
      const bf16x8 b0 = *(const bf16x8*)(kvh + lr * 32);
      const bf16x8 b1 = *(const bf16x8*)(kvh + (16 + lr) * 32);
      const f32x4 a0 = __builtin_amdgcn_mfma_f32_16x16x32_bf16(af, b0, zero, 0, 0, 0);
      const f32x4 a1 = __builtin_amdgcn_mfma_f32_16x16x32_bf16(af, b1, zero, 0, 0, 0);
      const int rbase = tt * 16 + kg * 4;
#pragma unroll
      for (int rg = 0; rg < 4; ++rg) {
        attn_s[(rbase + rg) * ASTRIDE + hd * 32 + lr]      = (bf16_t)a0[rg];
        attn_s[(rbase + rg) * ASTRIDE + hd * 32 + 16 + lr] = (bf16_t)a1[rg];
      }
    }
  }
  __syncthreads();

  const int c0 = lane * 8;
  const f32x4 w0 = *(const f32x4*)(n2w + c0), w1 = *(const f32x4*)(n2w + c0 + 4);
  const f32x4 bb0 = *(const f32x4*)(n2b + c0), bb1 = *(const f32x4*)(n2b + c0 + 4);
  for (int it = 0; it < 8; ++it) {
    const int tl = wv * 8 + it;
    const long tok = tok0 + tl;
    const f32x4 xa = *(const f32x4*)(x + tok * CC + c0);
    const f32x4 xb = *(const f32x4*)(x + tok * CC + c0 + 4);
    const bf16x8 hv = *(const bf16x8*)(h + tok * CC + c0);
    const bf16x8 av = *(const bf16x8*)&attn_s[tl * ASTRIDE + c0];
    float x2[8];
#pragma unroll
    for (int i = 0; i < 4; ++i) {
      x2[i]     = xa[i] + (float)hv[i]     + (float)av[i];
      x2[4 + i] = xb[i] + (float)hv[4 + i] + (float)av[4 + i];
    }
    float s = 0.f, s2 = 0.f;
#pragma unroll
    for (int i = 0; i < 8; ++i) { s += x2[i]; s2 += x2[i] * x2[i]; }
    for (int off = 32; off; off >>= 1) { s += __shfl_xor(s, off); s2 += __shfl_xor(s2, off); }
    const float mean = s * (1.f / CC);
    const float var  = fmaxf(s2 * (1.f / CC) - mean * mean, 0.f);
    const float rstd = rsqrtf(var + 1e-5f);
    f32x4 oa, ob;
    bf16x8 om;
#pragma unroll
    for (int i = 0; i < 4; ++i) {
      oa[i] = x2[i]; ob[i] = x2[4 + i];
      om[i]     = (bf16_t)(w0[i] * (x2[i] - mean) * rstd + bb0[i]);
      om[4 + i] = (bf16_t)(w1[i] * (x2[4 + i] - mean) * rstd + bb1[i]);
    }
    *(f32x4*)(xout + tok * CC + c0) = oa;
    *(f32x4*)(xout + tok * CC + c0 + 4) = ob;
    *(bf16x8*)(mout + tok * CC + c0) = om;
  }
}

// ---- GEMM: BM=256 x BN, BK=32, 8 waves (WMC x WNC), 3-buf distance-2 prefetch,
//      counted vmcnt, XOR-swizzled LDS (2-way free on fragment reads) ----
// out[i][j] = sum_k A[i][k] * Bw[j][k]
template <int K, int NOUT, int BN, int WMC, int WNC, bool GELU>
__global__ __launch_bounds__(512, 2) void gemm_kernel(const bf16_t* __restrict__ A,
                                                      const bf16_t* __restrict__ Bw,
                                                      const float* __restrict__ bias,
                                                      bf16_t* __restrict__ outb,
                                                      float* __restrict__ outf) {
  constexpr int ABYTES = 256 * 64;            // A tile bytes per buffer
  constexpr int BBYTES = BN * 64;
  constexpr int BUFB = ABYTES + BBYTES;
  constexpr int LOADS = BUFB / 8192;          // gload_lds16 per thread per tile (4 or 3)
  constexpr int MREP = 256 / WMC / 16;
  constexpr int NREP = BN / WNC / 16;
  constexpr int NTILE = NOUT / BN;
  constexpr int NT = K / 32;

  __shared__ bf16_t lds[3 * BUFB / 2];
  const int tid = threadIdx.x;
  const int wid = tid >> 6, lane = tid & 63;
  const int wm = wid / WNC, wn = wid % WNC;
  const int lr = lane & 15, kg = lane >> 4;

  int bid = blockIdx.x;
  const int q = gridDim.x >> 3;
  bid = (bid & 7) * q + (bid >> 3);
  const int bx = bid % NTILE;
  const long by = bid / NTILE;
  const long row0 = by * 256;
  const long col0 = (long)bx * BN;

  // staging: thread tid covers LDS bytes r*8192 + tid*16 (linear dest);
  // global column pre-swizzled so that LDS[row][chunk] holds logical chunk^((row>>1)&3)
  const int srow = tid >> 2;
  const int swc = ((tid & 3) ^ ((srow >> 1) & 3)) * 8;
  const bf16_t* gA = A + (row0 + srow) * (long)K + swc;
  const bf16_t* gB = Bw + (col0 + srow) * (long)K + swc;
  char* ldsb = (char*)lds;

#define STAGEK(bufi, kt) do {                                            \
    char* base_ = ldsb + (bufi) * BUFB;                                  \
    gload_lds16(gA + (kt) * 32,            base_ + tid * 16);            \
    gload_lds16(gA + 128L * K + (kt) * 32, base_ + 8192 + tid * 16);     \
    gload_lds16(gB + (kt) * 32,            base_ + ABYTES + tid * 16);   \
    if constexpr (BN == 256)                                             \
      gload_lds16(gB + 128L * K + (kt) * 32,                             \
                  base_ + ABYTES + 8192 + tid * 16);                     \
  } while (0)

  f32x4 acc[MREP][NREP] = {};

  STAGEK(0, 0);
  STAGEK(1, 1);
  if constexpr (LOADS == 4) asm volatile("s_waitcnt vmcnt(4)" ::: "memory");
  else                      asm volatile("s_waitcnt vmcnt(3)" ::: "memory");
  __builtin_amdgcn_s_barrier();

  for (int t = 0; t < NT; ++t) {
    const int cur = t % 3;
    if (t + 2 < NT) STAGEK((t + 2) % 3, t + 2);
    const char* ab = (const char*)ldsb + cur * BUFB;
    const char* bb = ab + ABYTES;
    bf16x8 af[MREP], bf[NREP];
#pragma unroll
    for (int m = 0; m < MREP; ++m) {
      const int row = wm * (256 / WMC) + m * 16 + lr;
      af[m] = *(const bf16x8*)(ab + row * 64 + ((kg ^ ((row >> 1) & 3)) * 16));
    }
#pragma unroll
    for (int n = 0; n < NREP; ++n) {
      const int row = wn * (BN / WNC) + n * 16 + lr;
      bf[n] = *(const bf16x8*)(bb + row * 64 + ((kg ^ ((row >> 1) & 3)) * 16));
    }
    __builtin_amdgcn_s_setprio(1);
#pragma unroll
    for (int m = 0; m < MREP; ++m)
#pragma unroll
      for (int n = 0; n < NREP; ++n)
        acc[m][n] = __builtin_amdgcn_mfma_f32_16x16x32_bf16(af[m], bf[n], acc[m][n], 0, 0, 0);
    __builtin_amdgcn_s_setprio(0);
    if (t + 1 < NT) {
      if (t + 2 < NT) {
        if constexpr (LOADS == 4) asm volatile("s_waitcnt vmcnt(4)" ::: "memory");
        else                      asm volatile("s_waitcnt vmcnt(3)" ::: "memory");
      } else {
        asm volatile("s_waitcnt vmcnt(0)" ::: "memory");
      }
      __builtin_amdgcn_s_barrier();
    }
  }
#undef STAGEK

  // epilogue: D row = kg*4 + rg, col = lr
#pragma unroll
  for (int n = 0; n < NREP; ++n) {
    const long col = col0 + wn * (BN / WNC) + n * 16 + lr;
    const float bs = bias[col];
#pragma unroll
    for (int m = 0; m < MREP; ++m) {
#pragma unroll
      for (int rg = 0; rg < 4; ++rg) {
        const long row = row0 + wm * (256 / WMC) + m * 16 + kg * 4 + rg;
        const float v = acc[m][n][rg] + bs;
        if constexpr (GELU) {
          const float u = 0.7978845608028654f * (v + 0.044715f * v * v * v);
          const float gv = v / (1.f + __expf(-2.f * u));
          outb[row * NOUT + col] = (bf16_t)gv;
        } else {
          outf[row * NOUT + col] += v;   // residual RMW onto x2 already in d_out
        }
      }
    }
  }
}

extern "C" void kernel_launch(void* const* d_in, const int* in_sizes, int n_in,
                              void* d_out, int out_size, void* d_ws, size_t ws_size,
                              hipStream_t stream) {
  const float* x   = (const float*)d_in[0];
  const float* n1w = (const float*)d_in[2];
  const float* n1b = (const float*)d_in[3];
  const float* klw = (const float*)d_in[4];
  const float* klb = (const float*)d_in[5];
  const float* vlw = (const float*)d_in[6];
  const float* vlb = (const float*)d_in[7];
  const float* n2w = (const float*)d_in[8];
  const float* n2b = (const float*)d_in[9];
  const float* w1f = (const float*)d_in[10];
  const float* b1  = (const float*)d_in[11];
  const float* w2f = (const float*)d_in[12];
  const float* b2  = (const float*)d_in[13];
  float* out = (float*)d_out;

  char* ws = (char*)d_ws;
  bf16_t* h   = (bf16_t*)(ws);                           // 64 MiB
  bf16_t* mb  = (bf16_t*)(ws + (size_t)67108864);        // 64 MiB
  bf16_t* act = (bf16_t*)(ws + (size_t)134217728);       // 64 MiB
  bf16_t* w1  = (bf16_t*)(ws + (size_t)201326592);       // 2 MiB
  bf16_t* w2  = (bf16_t*)(ws + (size_t)203423744);       // 2 MiB
  float*  kvp = (float*)(ws + (size_t)205520896);        // 16 MiB
  bf16_t* kvT = (bf16_t*)(ws + (size_t)222298112);       // 128 KiB

  cvt_bf16_kernel<<<1024, 256, 0, stream>>>(w1f, w1);
  cvt_bf16_kernel<<<1024, 256, 0, stream>>>(w2f, w2);
  norm1_kernel<<<MTOT / 4, 256, 0, stream>>>(x, n1w, n1b, h);
  kv_partial_kernel<<<BB * HH * 64, 256, 0, stream>>>(h, klw, klb, vlw, vlb, kvp);
  kv_reduce_kernel<<<BB * HH, 256, 0, stream>>>(kvp, kvT);
  attn_fused_kernel<<<MTOT / 32, 256, 0, stream>>>(x, h, kvT, n2w, n2b, out, mb);
  for (int ch = 0; ch < MTOT / MCHUNK; ++ch) {
    // GEMM1: 16384x2048x512, 256x256 tiles, waves 2x4 -> grid 512
    gemm_kernel<CC, HID, 256, 2, 4, true>
        <<<(MCHUNK / 256) * (HID / 256), 512, 0, stream>>>(
        mb + (long)ch * MCHUNK * CC, w1, b1, act, nullptr);
    // GEMM2: 16384x512x2048, 256x128 tiles, waves 4x2 -> grid 256
    gemm_kernel<HID, CC, 128, 4, 2, false>
        <<<(MCHUNK / 256) * (CC / 128), 512, 0, stream>>>(
        act, w2, b2, nullptr, out + (long)ch * MCHUNK * CC);
  }
}